// Round 5
// baseline (27.190 us; speedup 1.0000x reference)
//
#include <hip/hip_runtime.h>

// CoarseDirectionReducer: out[b, c*8+g, h, w] = sum_j softmax(logits)[g][j] * in[b, c*24+GI[g][j], h, w]
// B=4, nc=4, NUM_FINE=24, H=W=256. Memory-bound channel remix: 96 MB read + 32 MB write (minimal).
//
// One block per (plane, group, chunk): 3 read streams + 1 write stream per
// wave, 16 KB contiguous window per stream. Reads are nontemporal (each input
// byte used exactly once -> don't allocate in L2); stores are regular (L2
// write-combining / L3 absorption).

#define NUM_FINE 24
#define NGROUP 8
#define PIX4 16384        // 256*256/4
#define VEC 4             // float4s per thread
#define CHUNKS 16         // PIX4 / (256 threads * VEC)

typedef float v4f __attribute__((ext_vector_type(4)));  // native vector for nt builtins

__global__ __launch_bounds__(256) void coarse_reduce_kernel(
    const v4f* __restrict__ in,         // (16, 24, PIX4) float4
    const float* __restrict__ logits,   // (8, 3)
    v4f* __restrict__ out)              // (16, 8, PIX4) float4
{
    // blockIdx.x = plane*(8*CHUNKS) + g*CHUNKS + chunk
    const int chunk = blockIdx.x & (CHUNKS - 1);
    const int g     = (blockIdx.x >> 4) & (NGROUP - 1);
    const int plane = blockIdx.x >> 7;

    // GROUP_IDX precomputed from the reference's GROUPS_DXDY / offset table.
    constexpr int gi[NGROUP][3] = {
        {17, 23, 18},
        {16, 21, 22},
        {15, 19, 20},
        {12, 13,  9},
        {11, 10, 14},
        { 8,  4,  3},
        { 7,  2,  1},
        { 6,  0,  5},
    };

    // Wave-uniform softmax weights for this group (scalarized by compiler).
    const float a = logits[g * 3 + 0];
    const float b = logits[g * 3 + 1];
    const float c = logits[g * 3 + 2];
    const float m  = fmaxf(a, fmaxf(b, c));
    const float ea = __expf(a - m), eb = __expf(b - m), ec = __expf(c - m);
    const float inv = 1.0f / (ea + eb + ec);
    const float w0 = ea * inv, w1 = eb * inv, w2 = ec * inv;

    const int base = chunk * (256 * VEC) + threadIdx.x;  // float4 index in channel plane

    const v4f* i0 = in + (size_t)(plane * NUM_FINE + gi[g][0]) * PIX4 + base;
    const v4f* i1 = in + (size_t)(plane * NUM_FINE + gi[g][1]) * PIX4 + base;
    const v4f* i2 = in + (size_t)(plane * NUM_FINE + gi[g][2]) * PIX4 + base;
    v4f*       ob = out + (size_t)(plane * NGROUP + g) * PIX4 + base;

    // Issue all loads first (12 independent 16 B nontemporal loads in flight).
    v4f x0[VEC], x1[VEC], x2[VEC];
#pragma unroll
    for (int k = 0; k < VEC; ++k) x0[k] = __builtin_nontemporal_load(&i0[k * 256]);
#pragma unroll
    for (int k = 0; k < VEC; ++k) x1[k] = __builtin_nontemporal_load(&i1[k * 256]);
#pragma unroll
    for (int k = 0; k < VEC; ++k) x2[k] = __builtin_nontemporal_load(&i2[k * 256]);

#pragma unroll
    for (int k = 0; k < VEC; ++k) {
        v4f r = w0 * x0[k] + w1 * x1[k] + w2 * x2[k];
        ob[k * 256] = r;
    }
}

extern "C" void kernel_launch(void* const* d_in, const int* in_sizes, int n_in,
                              void* d_out, int out_size, void* d_ws, size_t ws_size,
                              hipStream_t stream) {
    const float* in     = (const float*)d_in[0];  // (4, 96, 256, 256) f32
    const float* logits = (const float*)d_in[1];  // (8, 3) f32
    float* out          = (float*)d_out;          // (4, 32, 256, 256) f32

    const int grid = 16 * NGROUP * CHUNKS;        // 2048 blocks
    coarse_reduce_kernel<<<grid, 256, 0, stream>>>(
        (const v4f*)in, logits, (v4f*)out);
}

// Round 6
// 24.522 us; speedup vs baseline: 1.1088x; 1.1088x over previous
//
#include <hip/hip_runtime.h>

// CoarseDirectionReducer: out[b, c*8+g, h, w] = sum_j softmax(logits)[g][j] * in[b, c*24+GI[g][j], h, w]
// B=4, nc=4, NUM_FINE=24, H=W=256. Memory-bound channel remix: 96 MB read + 32 MB write (minimal).
//
// Best-measured config (R2): one block per (plane, group, chunk) -> exactly
// 3 read streams + 1 write stream per wave, 8 KB contiguous window per stream,
// 2 float4 per thread, regular (cached) loads and stores.
// Measured: 24.5 us (~5.2 TB/s effective incl. launch overhead).
// nt-store (R4: 24.95) and nt-load (R5: 27.19) both regressed — cache path helps.

#define NUM_FINE 24
#define NGROUP 8
#define PIX4 16384        // 256*256/4
#define CHUNKS 32         // PIX4 / (256 threads * 2 float4)

__global__ __launch_bounds__(256) void coarse_reduce_kernel(
    const float4* __restrict__ in,      // (16, 24, PIX4) float4
    const float*  __restrict__ logits,  // (8, 3)
    float4* __restrict__ out)           // (16, 8, PIX4) float4
{
    // blockIdx.x = plane*(8*CHUNKS) + g*CHUNKS + chunk
    const int chunk = blockIdx.x & (CHUNKS - 1);
    const int g     = (blockIdx.x >> 5) & (NGROUP - 1);
    const int plane = blockIdx.x >> 8;

    // GROUP_IDX precomputed from the reference's GROUPS_DXDY / offset table.
    constexpr int gi[NGROUP][3] = {
        {17, 23, 18},
        {16, 21, 22},
        {15, 19, 20},
        {12, 13,  9},
        {11, 10, 14},
        { 8,  4,  3},
        { 7,  2,  1},
        { 6,  0,  5},
    };

    // Wave-uniform softmax weights for this group (compiler scalarizes).
    const float a = logits[g * 3 + 0];
    const float b = logits[g * 3 + 1];
    const float c = logits[g * 3 + 2];
    const float m  = fmaxf(a, fmaxf(b, c));
    const float ea = __expf(a - m), eb = __expf(b - m), ec = __expf(c - m);
    const float inv = 1.0f / (ea + eb + ec);
    const float w0 = ea * inv, w1 = eb * inv, w2 = ec * inv;

    const int base = chunk * 512 + threadIdx.x;  // float4 index within a channel plane

    const float4* i0 = in + (size_t)(plane * NUM_FINE + gi[g][0]) * PIX4 + base;
    const float4* i1 = in + (size_t)(plane * NUM_FINE + gi[g][1]) * PIX4 + base;
    const float4* i2 = in + (size_t)(plane * NUM_FINE + gi[g][2]) * PIX4 + base;
    float4*       ob = out + (size_t)(plane * NGROUP + g) * PIX4 + base;

#pragma unroll
    for (int k = 0; k < 2; ++k) {
        const float4 x0 = i0[k * 256];
        const float4 x1 = i1[k * 256];
        const float4 x2 = i2[k * 256];
        float4 r;
        r.x = w0 * x0.x + w1 * x1.x + w2 * x2.x;
        r.y = w0 * x0.y + w1 * x1.y + w2 * x2.y;
        r.z = w0 * x0.z + w1 * x1.z + w2 * x2.z;
        r.w = w0 * x0.w + w1 * x1.w + w2 * x2.w;
        ob[k * 256] = r;
    }
}

extern "C" void kernel_launch(void* const* d_in, const int* in_sizes, int n_in,
                              void* d_out, int out_size, void* d_ws, size_t ws_size,
                              hipStream_t stream) {
    const float* in     = (const float*)d_in[0];  // (4, 96, 256, 256) f32
    const float* logits = (const float*)d_in[1];  // (8, 3) f32
    float* out          = (float*)d_out;          // (4, 32, 256, 256) f32

    const int grid = 16 * NGROUP * CHUNKS;        // 4096 blocks
    coarse_reduce_kernel<<<grid, 256, 0, stream>>>(
        (const float4*)in, logits, (float4*)out);
}